// Round 1
// baseline (1640.613 us; speedup 1.0000x reference)
//
#include <hip/hip_runtime.h>

// Problem constants: S=1024, B=8, E=1024, H=16, HD=64
#define M_TOK 8192   // S*B
#define SEQ   1024
#define NB    8
#define EMB   1024
#define NH    16

typedef float  f32x4 __attribute__((ext_vector_type(4)));
typedef __bf16 bf16x8 __attribute__((ext_vector_type(8)));
typedef unsigned short u16x8 __attribute__((ext_vector_type(8)));
typedef unsigned short u16x4 __attribute__((ext_vector_type(4)));

__device__ __forceinline__ unsigned short f2bf(float f) {
  unsigned int u = __builtin_bit_cast(unsigned int, f);
  return (unsigned short)((u + 0x7fffu + ((u >> 16) & 1u)) >> 16);
}

__device__ __forceinline__ f32x4 mfma_bf16(u16x8 a, u16x8 b, f32x4 c) {
  return __builtin_amdgcn_mfma_f32_16x16x32_bf16(
      __builtin_bit_cast(bf16x8, a), __builtin_bit_cast(bf16x8, b), c, 0, 0, 0);
}

__device__ __forceinline__ void gload_lds16(const void* g, void* l) {
  __builtin_amdgcn_global_load_lds(
      (const __attribute__((address_space(1))) void*)g,
      (__attribute__((address_space(3))) void*)l, 16, 0, 0);
}

// ---------------------------------------------------------------- converts
__global__ __launch_bounds__(256) void cvt_kernel(const float* __restrict__ src,
                                                  unsigned short* __restrict__ dst,
                                                  int n) {
  int i = (blockIdx.x * 256 + threadIdx.x) * 4;
  if (i >= n) return;
  float4 v = *reinterpret_cast<const float4*>(src + i);
  u16x4 o = {f2bf(v.x), f2bf(v.y), f2bf(v.z), f2bf(v.w)};
  *reinterpret_cast<u16x4*>(dst + i) = o;
}

// ---------------------------------------------------------------- QKV proj
// C[m,n] = X_sec[m,:] . W[n,:]  (complex), m in [0,8192), n in [0,3072)
// writes q2/k2: (B,H,S,128) bf16 (re|im on d axis), vt: (B,H,128,S) bf16
__global__ __launch_bounds__(256, 2) void proj_gemm(
    const float* __restrict__ qre, const float* __restrict__ qim,
    const float* __restrict__ kre, const float* __restrict__ kim,
    const float* __restrict__ vre, const float* __restrict__ vim,
    const unsigned short* __restrict__ wr, const unsigned short* __restrict__ wi,
    const float* __restrict__ br, const float* __restrict__ bi,
    unsigned short* __restrict__ q2, unsigned short* __restrict__ k2,
    unsigned short* __restrict__ vt) {
  __shared__ unsigned short sA[2][128][40];  // +8 pad: conflict-free b128 reads
  __shared__ unsigned short sW[2][128][32];

  const int tid = threadIdx.x;
  const int lane = tid & 63;
  const int w = tid >> 6;
  const int lr = lane & 15, lk = lane >> 4;
  const int wm = (w & 1) * 64, wn = (w >> 1) * 64;
  const int m0 = blockIdx.x * 128;
  const int n0 = blockIdx.y * 128;
  const int sec = n0 >> 10;

  const float* aRe = (sec == 0) ? qre : ((sec == 1) ? kre : vre);
  const float* aIm = (sec == 0) ? qim : ((sec == 1) ? kim : vim);

  const int srow = tid >> 1;   // 0..127
  const int shalf = tid & 1;   // 0..1
  const float* gARe = aRe + (size_t)(m0 + srow) * 1024 + shalf * 16;
  const float* gAIm = aIm + (size_t)(m0 + srow) * 1024 + shalf * 16;

  f32x4 accre[4][4], accim[4][4];
  for (int i = 0; i < 4; ++i)
    for (int j = 0; j < 4; ++j) {
      accre[i][j] = {0.f, 0.f, 0.f, 0.f};
      accim[i][j] = {0.f, 0.f, 0.f, 0.f};
    }
  const u16x8 sign8 = {0x8000, 0x8000, 0x8000, 0x8000, 0x8000, 0x8000, 0x8000, 0x8000};

  for (int k0 = 0; k0 < 1024; k0 += 32) {
    // async W staging (bf16 already)
    for (int c = 0; c < 2; ++c) {
      int cw = w * 2 + c;
      int row = cw * 16 + (lane >> 2);
      int slot = lane & 3;
      size_t goff = (size_t)(n0 + row) * 1024 + k0 + slot * 8;
      gload_lds16(wr + goff, &sW[0][cw * 16][0]);
      gload_lds16(wi + goff, &sW[1][cw * 16][0]);
    }
    // reg-staged A with f32->bf16
    {
      float4 r0 = *(const float4*)(gARe + k0);
      float4 r1 = *(const float4*)(gARe + k0 + 4);
      float4 r2 = *(const float4*)(gARe + k0 + 8);
      float4 r3 = *(const float4*)(gARe + k0 + 12);
      u16x8 p0 = {f2bf(r0.x), f2bf(r0.y), f2bf(r0.z), f2bf(r0.w),
                  f2bf(r1.x), f2bf(r1.y), f2bf(r1.z), f2bf(r1.w)};
      u16x8 p1 = {f2bf(r2.x), f2bf(r2.y), f2bf(r2.z), f2bf(r2.w),
                  f2bf(r3.x), f2bf(r3.y), f2bf(r3.z), f2bf(r3.w)};
      *(u16x8*)&sA[0][srow][shalf * 16] = p0;
      *(u16x8*)&sA[0][srow][shalf * 16 + 8] = p1;
      float4 i0 = *(const float4*)(gAIm + k0);
      float4 i1 = *(const float4*)(gAIm + k0 + 4);
      float4 i2 = *(const float4*)(gAIm + k0 + 8);
      float4 i3 = *(const float4*)(gAIm + k0 + 12);
      u16x8 p2 = {f2bf(i0.x), f2bf(i0.y), f2bf(i0.z), f2bf(i0.w),
                  f2bf(i1.x), f2bf(i1.y), f2bf(i1.z), f2bf(i1.w)};
      u16x8 p3 = {f2bf(i2.x), f2bf(i2.y), f2bf(i2.z), f2bf(i2.w),
                  f2bf(i3.x), f2bf(i3.y), f2bf(i3.z), f2bf(i3.w)};
      *(u16x8*)&sA[1][srow][shalf * 16] = p2;
      *(u16x8*)&sA[1][srow][shalf * 16 + 8] = p3;
    }
    __syncthreads();

    u16x8 fWr[4], fWi[4];
    for (int ni = 0; ni < 4; ++ni) {
      fWr[ni] = *(const u16x8*)&sW[0][wn + ni * 16 + lr][lk * 8];
      fWi[ni] = *(const u16x8*)&sW[1][wn + ni * 16 + lr][lk * 8];
    }
    for (int mi = 0; mi < 4; ++mi) {
      u16x8 ar = *(const u16x8*)&sA[0][wm + mi * 16 + lr][lk * 8];
      u16x8 ai = *(const u16x8*)&sA[1][wm + mi * 16 + lr][lk * 8];
      u16x8 nai = ai ^ sign8;
      for (int ni = 0; ni < 4; ++ni) {
        accre[mi][ni] = mfma_bf16(ar, fWr[ni], accre[mi][ni]);
        accre[mi][ni] = mfma_bf16(nai, fWi[ni], accre[mi][ni]);
        accim[mi][ni] = mfma_bf16(ar, fWi[ni], accim[mi][ni]);
        accim[mi][ni] = mfma_bf16(ai, fWr[ni], accim[mi][ni]);
      }
    }
    __syncthreads();
  }

  // epilogue: bias + scatter to q2/k2/vt
  for (int ni = 0; ni < 4; ++ni) {
    int nabs = n0 + wn + ni * 16 + lr;
    int nl = nabs & 1023;
    int h = nl >> 6, d = nl & 63;
    float vbr = br[nabs], vbi = bi[nabs];
    for (int mi = 0; mi < 4; ++mi) {
      for (int r = 0; r < 4; ++r) {
        int m = m0 + wm + mi * 16 + lk * 4 + r;
        int ss = m >> 3, bb = m & 7;
        float re = accre[mi][ni][r] + vbr;
        float im = accim[mi][ni][r] + vbi;
        int bh = bb * 16 + h;
        if (sec == 2) {
          size_t base = ((size_t)bh * 128 + d) * 1024 + ss;
          vt[base] = f2bf(re);
          vt[base + 65536] = f2bf(im);
        } else {
          unsigned short* dst = (sec == 0) ? q2 : k2;
          size_t base = ((size_t)bh * 1024 + ss) * 128;
          dst[base + d] = f2bf(re);
          dst[base + 64 + d] = f2bf(im);
        }
      }
    }
  }
}

// ---------------------------------------------------------------- attention
// grid (128 bh, 16 qtiles), 256 thr = 4 waves x 16 q-rows, flash online softmax
__global__ __launch_bounds__(256, 2) void attn_kernel(
    const unsigned short* __restrict__ q2, const unsigned short* __restrict__ k2,
    const unsigned short* __restrict__ vt,
    unsigned short* __restrict__ aor, unsigned short* __restrict__ aoi) {
  __shared__ unsigned short sQ[64][128];
  __shared__ unsigned short sK[64][128];
  __shared__ unsigned short sV[128][64];
  __shared__ unsigned short sP[4][16][72];  // +8 pad -> conflict-free A reads

  const int tid = threadIdx.x, lane = tid & 63, w = tid >> 6;
  const int lr = lane & 15, lk = lane >> 4;
  const int bh = blockIdx.x;
  const int q0 = blockIdx.y * 64;
  const int bb = bh >> 4, hh = bh & 15;

  // stage Q tile (64 x 128) once
  const unsigned short* qbase = q2 + (size_t)bh * 131072 + (size_t)q0 * 128;
  for (int c = 0; c < 4; ++c) {
    int rb = (w * 4 + c) * 4;
    gload_lds16(qbase + (size_t)(rb + (lane >> 4)) * 128 + (lane & 15) * 8,
                &sQ[rb][0]);
  }

  f32x4 o[8];
  for (int i = 0; i < 8; ++i) o[i] = {0.f, 0.f, 0.f, 0.f};
  float mrun[4] = {-1e30f, -1e30f, -1e30f, -1e30f};
  float lrun[4] = {0.f, 0.f, 0.f, 0.f};
  const float SC = 0.125f;  // 1/sqrt(64)

  for (int t0 = 0; t0 < 1024; t0 += 64) {
    const unsigned short* kb = k2 + (size_t)bh * 131072 + (size_t)t0 * 128;
    for (int c = 0; c < 4; ++c) {
      int rb = (w * 4 + c) * 4;
      gload_lds16(kb + (size_t)(rb + (lane >> 4)) * 128 + (lane & 15) * 8,
                  &sK[rb][0]);
    }
    const unsigned short* vb = vt + (size_t)bh * 131072 + t0;
    for (int c = 0; c < 4; ++c) {
      int rb = (w * 4 + c) * 8;
      gload_lds16(vb + (size_t)(rb + (lane >> 3)) * 1024 + (lane & 7) * 8,
                  &sV[rb][0]);
    }
    __syncthreads();

    // scores tile: rows = wave's 16 q-rows, cols = 64 t
    f32x4 sc[4];
    for (int nj = 0; nj < 4; ++nj) sc[nj] = {0.f, 0.f, 0.f, 0.f};
    for (int ks = 0; ks < 4; ++ks) {
      u16x8 qf = *(const u16x8*)&sQ[w * 16 + lr][ks * 32 + lk * 8];
      for (int nj = 0; nj < 4; ++nj) {
        u16x8 kf = *(const u16x8*)&sK[nj * 16 + lr][ks * 32 + lk * 8];
        sc[nj] = mfma_bf16(qf, kf, sc[nj]);
      }
    }

    // online softmax (row r of this lane = 4*lk + r)
    for (int r = 0; r < 4; ++r) {
      float s0 = sc[0][r] * SC, s1 = sc[1][r] * SC;
      float s2 = sc[2][r] * SC, s3 = sc[3][r] * SC;
      float mx = fmaxf(fmaxf(s0, s1), fmaxf(s2, s3));
      for (int msk = 1; msk < 16; msk <<= 1) mx = fmaxf(mx, __shfl_xor(mx, msk));
      float mnew = fmaxf(mrun[r], mx);
      float corr = __expf(mrun[r] - mnew);
      float p0 = __expf(s0 - mnew), p1 = __expf(s1 - mnew);
      float p2 = __expf(s2 - mnew), p3 = __expf(s3 - mnew);
      float rs = p0 + p1 + p2 + p3;
      for (int msk = 1; msk < 16; msk <<= 1) rs += __shfl_xor(rs, msk);
      lrun[r] = lrun[r] * corr + rs;
      mrun[r] = mnew;
      for (int ni = 0; ni < 8; ++ni) o[ni][r] *= corr;
      int prow = lk * 4 + r;
      sP[w][prow][0 * 16 + lr] = f2bf(p0);
      sP[w][prow][1 * 16 + lr] = f2bf(p1);
      sP[w][prow][2 * 16 + lr] = f2bf(p2);
      sP[w][prow][3 * 16 + lr] = f2bf(p3);
    }

    // PV: O[s, dd] += P[s, t] * VT[dd, t]
    for (int ks = 0; ks < 2; ++ks) {
      u16x8 pf = *(const u16x8*)&sP[w][lr][ks * 32 + lk * 8];
      for (int ni = 0; ni < 8; ++ni) {
        u16x8 vf = *(const u16x8*)&sV[ni * 16 + lr][ks * 32 + lk * 8];
        o[ni] = mfma_bf16(pf, vf, o[ni]);
      }
    }
    __syncthreads();
  }

  for (int r = 0; r < 4; ++r) {
    float inv = 1.0f / lrun[r];
    for (int ni = 0; ni < 8; ++ni) o[ni][r] *= inv;
  }
  for (int ni = 0; ni < 8; ++ni) {
    int dd = ni * 16 + lr;
    for (int r = 0; r < 4; ++r) {
      int sg = q0 + w * 16 + lk * 4 + r;
      size_t tok = (size_t)sg * 8 + bb;
      if (dd < 64)
        aor[tok * 1024 + hh * 64 + dd] = f2bf(o[ni][r]);
      else
        aoi[tok * 1024 + hh * 64 + (dd - 64)] = f2bf(o[ni][r]);
    }
  }
}

// ---------------------------------------------------------------- out proj
__global__ __launch_bounds__(256, 2) void out_gemm(
    const unsigned short* __restrict__ ar, const unsigned short* __restrict__ ai,
    const unsigned short* __restrict__ wr, const unsigned short* __restrict__ wi,
    const float* __restrict__ br, const float* __restrict__ bi,
    float* __restrict__ out) {
  __shared__ unsigned short sA[2][128][32];
  __shared__ unsigned short sW[2][128][32];

  const int tid = threadIdx.x;
  const int lane = tid & 63;
  const int w = tid >> 6;
  const int lr = lane & 15, lk = lane >> 4;
  const int wm = (w & 1) * 64, wn = (w >> 1) * 64;
  const int m0 = blockIdx.x * 128;
  const int n0 = blockIdx.y * 128;

  f32x4 accre[4][4], accim[4][4];
  for (int i = 0; i < 4; ++i)
    for (int j = 0; j < 4; ++j) {
      accre[i][j] = {0.f, 0.f, 0.f, 0.f};
      accim[i][j] = {0.f, 0.f, 0.f, 0.f};
    }
  const u16x8 sign8 = {0x8000, 0x8000, 0x8000, 0x8000, 0x8000, 0x8000, 0x8000, 0x8000};

  for (int k0 = 0; k0 < 1024; k0 += 32) {
    for (int c = 0; c < 2; ++c) {
      int cw = w * 2 + c;
      int row = cw * 16 + (lane >> 2);
      int slot = lane & 3;
      size_t ga = (size_t)(m0 + row) * 1024 + k0 + slot * 8;
      size_t gw = (size_t)(n0 + row) * 1024 + k0 + slot * 8;
      gload_lds16(ar + ga, &sA[0][cw * 16][0]);
      gload_lds16(ai + ga, &sA[1][cw * 16][0]);
      gload_lds16(wr + gw, &sW[0][cw * 16][0]);
      gload_lds16(wi + gw, &sW[1][cw * 16][0]);
    }
    __syncthreads();

    u16x8 fWr[4], fWi[4];
    for (int ni = 0; ni < 4; ++ni) {
      fWr[ni] = *(const u16x8*)&sW[0][wn + ni * 16 + lr][lk * 8];
      fWi[ni] = *(const u16x8*)&sW[1][wn + ni * 16 + lr][lk * 8];
    }
    for (int mi = 0; mi < 4; ++mi) {
      u16x8 a_r = *(const u16x8*)&sA[0][wm + mi * 16 + lr][lk * 8];
      u16x8 a_i = *(const u16x8*)&sA[1][wm + mi * 16 + lr][lk * 8];
      u16x8 na_i = a_i ^ sign8;
      for (int ni = 0; ni < 4; ++ni) {
        accre[mi][ni] = mfma_bf16(a_r, fWr[ni], accre[mi][ni]);
        accre[mi][ni] = mfma_bf16(na_i, fWi[ni], accre[mi][ni]);
        accim[mi][ni] = mfma_bf16(a_r, fWi[ni], accim[mi][ni]);
        accim[mi][ni] = mfma_bf16(a_i, fWr[ni], accim[mi][ni]);
      }
    }
    __syncthreads();
  }

  for (int ni = 0; ni < 4; ++ni) {
    int n = n0 + wn + ni * 16 + lr;
    float vbr = br[n], vbi = bi[n];
    for (int mi = 0; mi < 4; ++mi) {
      for (int r = 0; r < 4; ++r) {
        int m = m0 + wm + mi * 16 + lk * 4 + r;
        out[(size_t)m * 1024 + n] = accre[mi][ni][r] + vbr;
        out[8388608 + (size_t)m * 1024 + n] = accim[mi][ni][r] + vbi;
      }
    }
  }
}

// ---------------------------------------------------------------- launch
extern "C" void kernel_launch(void* const* d_in, const int* in_sizes, int n_in,
                              void* d_out, int out_size, void* d_ws, size_t ws_size,
                              hipStream_t stream) {
  const float* qre = (const float*)d_in[0];
  const float* qim = (const float*)d_in[1];
  const float* kre = (const float*)d_in[2];
  const float* kim = (const float*)d_in[3];
  const float* vre = (const float*)d_in[4];
  const float* vim = (const float*)d_in[5];
  const float* wqkv_re = (const float*)d_in[6];
  const float* wqkv_im = (const float*)d_in[7];
  const float* bqr = (const float*)d_in[8];
  const float* bqi = (const float*)d_in[9];
  const float* wo_re = (const float*)d_in[10];
  const float* wo_im = (const float*)d_in[11];
  const float* bor = (const float*)d_in[12];
  const float* boi = (const float*)d_in[13];

  char* ws = (char*)d_ws;
  unsigned short* wr_bf  = (unsigned short*)(ws + 0);          //  6.29 MB
  unsigned short* wi_bf  = (unsigned short*)(ws + 6291456);    //  6.29 MB
  unsigned short* wor_bf = (unsigned short*)(ws + 12582912);   //  2.10 MB
  unsigned short* woi_bf = (unsigned short*)(ws + 14680064);   //  2.10 MB
  unsigned short* q2     = (unsigned short*)(ws + 16777216);   // 33.55 MB
  unsigned short* k2     = (unsigned short*)(ws + 50331648);   // 33.55 MB
  unsigned short* vt     = (unsigned short*)(ws + 83886080);   // 33.55 MB
  unsigned short* aor    = (unsigned short*)(ws + 117440512);  // 16.78 MB
  unsigned short* aoi    = (unsigned short*)(ws + 134217728);  // 16.78 MB (end 150.99 MB)

  cvt_kernel<<<3072, 256, 0, stream>>>(wqkv_re, wr_bf, 3145728);
  cvt_kernel<<<3072, 256, 0, stream>>>(wqkv_im, wi_bf, 3145728);
  cvt_kernel<<<1024, 256, 0, stream>>>(wo_re, wor_bf, 1048576);
  cvt_kernel<<<1024, 256, 0, stream>>>(wo_im, woi_bf, 1048576);

  proj_gemm<<<dim3(64, 24), 256, 0, stream>>>(qre, qim, kre, kim, vre, vim,
                                              wr_bf, wi_bf, bqr, bqi, q2, k2, vt);
  attn_kernel<<<dim3(128, 16), 256, 0, stream>>>(q2, k2, vt, aor, aoi);
  out_gemm<<<dim3(64, 8), 256, 0, stream>>>(aor, aoi, wor_bf, woi_bf, bor, boi,
                                            (float*)d_out);
}

// Round 2
// 671.927 us; speedup vs baseline: 2.4417x; 2.4417x over previous
//
#include <hip/hip_runtime.h>

// Problem constants: S=1024, B=8, E=1024, H=16, HD=64
#define M_TOK 8192   // S*B
#define SEQ   1024
#define NB    8
#define EMB   1024
#define NH    16

typedef float  f32x4 __attribute__((ext_vector_type(4)));
typedef __bf16 bf16x8 __attribute__((ext_vector_type(8)));
typedef unsigned short u16x8 __attribute__((ext_vector_type(8)));
typedef unsigned short u16x4 __attribute__((ext_vector_type(4)));

__device__ __forceinline__ unsigned short f2bf(float f) {
  unsigned int u = __builtin_bit_cast(unsigned int, f);
  return (unsigned short)((u + 0x7fffu + ((u >> 16) & 1u)) >> 16);
}

__device__ __forceinline__ f32x4 mfma_bf16(u16x8 a, u16x8 b, f32x4 c) {
  return __builtin_amdgcn_mfma_f32_16x16x32_bf16(
      __builtin_bit_cast(bf16x8, a), __builtin_bit_cast(bf16x8, b), c, 0, 0, 0);
}

__device__ __forceinline__ void gload_lds16(const void* g, void* l) {
  __builtin_amdgcn_global_load_lds(
      (const __attribute__((address_space(1))) void*)g,
      (__attribute__((address_space(3))) void*)l, 16, 0, 0);
}

// ---------------------------------------------------------------- converts
__global__ __launch_bounds__(256) void cvt_kernel(const float* __restrict__ src,
                                                  unsigned short* __restrict__ dst,
                                                  int n) {
  int i = (blockIdx.x * 256 + threadIdx.x) * 4;
  if (i >= n) return;
  float4 v = *reinterpret_cast<const float4*>(src + i);
  u16x4 o = {f2bf(v.x), f2bf(v.y), f2bf(v.z), f2bf(v.w)};
  *reinterpret_cast<u16x4*>(dst + i) = o;
}

// ---------------------------------------------------------------- QKV proj
// Per-batch m-tiles: block handles 128 consecutive s at fixed b.
// writes q2/k2: (B,H,S,128) bf16 (re|im on d axis), vt: (B,H,128,S) bf16
__global__ __launch_bounds__(256, 2) void proj_gemm(
    const float* __restrict__ qre, const float* __restrict__ qim,
    const float* __restrict__ kre, const float* __restrict__ kim,
    const float* __restrict__ vre, const float* __restrict__ vim,
    const unsigned short* __restrict__ wr, const unsigned short* __restrict__ wi,
    const float* __restrict__ br, const float* __restrict__ bi,
    unsigned short* __restrict__ q2, unsigned short* __restrict__ k2,
    unsigned short* __restrict__ vt) {
  // one aliased LDS pool: K-loop uses sA(re,im)+sW(re,im); epilogue reuses as sC/sCt
  __shared__ __align__(16) unsigned short smem[18432];  // 36864 B
  unsigned short (*sA0)[40] = (unsigned short (*)[40])(smem);            // [128][40]
  unsigned short (*sA1)[40] = (unsigned short (*)[40])(smem + 5120);
  unsigned short (*sW0)[32] = (unsigned short (*)[32])(smem + 10240);    // [128][32]
  unsigned short (*sW1)[32] = (unsigned short (*)[32])(smem + 14336);
  unsigned short (*sC)[140]  = (unsigned short (*)[140])(smem);          // m-major stage
  unsigned short (*sCt)[144] = (unsigned short (*)[144])(smem);         // n-major stage

  const int tid = threadIdx.x;
  const int lane = tid & 63;
  const int w = tid >> 6;
  const int lr = lane & 15, lk = lane >> 4;
  const int wm = (w & 1) * 64, wn = (w >> 1) * 64;
  const int n0 = blockIdx.x * 128;
  const int sec = n0 >> 10;
  const int bb = blockIdx.y & 7;
  const int ss0 = (blockIdx.y >> 3) * 128;
  const int h_base = (n0 & 1023) >> 6;

  const float* aRe = (sec == 0) ? qre : ((sec == 1) ? kre : vre);
  const float* aIm = (sec == 0) ? qim : ((sec == 1) ? kim : vim);

  const int srow = tid >> 1;   // 0..127 (local s)
  const int shalf = tid & 1;   // 0..1
  const size_t arow = (size_t)((ss0 + srow) * 8 + bb) * 1024 + shalf * 16;
  const float* gARe = aRe + arow;
  const float* gAIm = aIm + arow;

  f32x4 accre[4][4], accim[4][4];
  for (int i = 0; i < 4; ++i)
    for (int j = 0; j < 4; ++j) {
      accre[i][j] = {0.f, 0.f, 0.f, 0.f};
      accim[i][j] = {0.f, 0.f, 0.f, 0.f};
    }
  const u16x8 sign8 = {0x8000, 0x8000, 0x8000, 0x8000, 0x8000, 0x8000, 0x8000, 0x8000};

  for (int k0 = 0; k0 < 1024; k0 += 32) {
    // async W staging (bf16 already)
    for (int c = 0; c < 2; ++c) {
      int cw = w * 2 + c;
      int row = cw * 16 + (lane >> 2);
      int slot = lane & 3;
      size_t goff = (size_t)(n0 + row) * 1024 + k0 + slot * 8;
      gload_lds16(wr + goff, &sW0[cw * 16][0]);
      gload_lds16(wi + goff, &sW1[cw * 16][0]);
    }
    // reg-staged A with f32->bf16
    {
      float4 r0 = *(const float4*)(gARe + k0);
      float4 r1 = *(const float4*)(gARe + k0 + 4);
      float4 r2 = *(const float4*)(gARe + k0 + 8);
      float4 r3 = *(const float4*)(gARe + k0 + 12);
      u16x8 p0 = {f2bf(r0.x), f2bf(r0.y), f2bf(r0.z), f2bf(r0.w),
                  f2bf(r1.x), f2bf(r1.y), f2bf(r1.z), f2bf(r1.w)};
      u16x8 p1 = {f2bf(r2.x), f2bf(r2.y), f2bf(r2.z), f2bf(r2.w),
                  f2bf(r3.x), f2bf(r3.y), f2bf(r3.z), f2bf(r3.w)};
      *(u16x8*)&sA0[srow][shalf * 16] = p0;
      *(u16x8*)&sA0[srow][shalf * 16 + 8] = p1;
      float4 i0 = *(const float4*)(gAIm + k0);
      float4 i1 = *(const float4*)(gAIm + k0 + 4);
      float4 i2 = *(const float4*)(gAIm + k0 + 8);
      float4 i3 = *(const float4*)(gAIm + k0 + 12);
      u16x8 p2 = {f2bf(i0.x), f2bf(i0.y), f2bf(i0.z), f2bf(i0.w),
                  f2bf(i1.x), f2bf(i1.y), f2bf(i1.z), f2bf(i1.w)};
      u16x8 p3 = {f2bf(i2.x), f2bf(i2.y), f2bf(i2.z), f2bf(i2.w),
                  f2bf(i3.x), f2bf(i3.y), f2bf(i3.z), f2bf(i3.w)};
      *(u16x8*)&sA1[srow][shalf * 16] = p2;
      *(u16x8*)&sA1[srow][shalf * 16 + 8] = p3;
    }
    __syncthreads();

    u16x8 fWr[4], fWi[4];
    for (int ni = 0; ni < 4; ++ni) {
      fWr[ni] = *(const u16x8*)&sW0[wn + ni * 16 + lr][lk * 8];
      fWi[ni] = *(const u16x8*)&sW1[wn + ni * 16 + lr][lk * 8];
    }
    for (int mi = 0; mi < 4; ++mi) {
      u16x8 ar = *(const u16x8*)&sA0[wm + mi * 16 + lr][lk * 8];
      u16x8 ai = *(const u16x8*)&sA1[wm + mi * 16 + lr][lk * 8];
      u16x8 nai = ai ^ sign8;
      for (int ni = 0; ni < 4; ++ni) {
        accre[mi][ni] = mfma_bf16(ar, fWr[ni], accre[mi][ni]);
        accre[mi][ni] = mfma_bf16(nai, fWi[ni], accre[mi][ni]);
        accim[mi][ni] = mfma_bf16(ar, fWi[ni], accim[mi][ni]);
        accim[mi][ni] = mfma_bf16(ai, fWr[ni], accim[mi][ni]);
      }
    }
    __syncthreads();
  }

  // bias values per lane-column
  float vbr[4], vbi[4];
  for (int ni = 0; ni < 4; ++ni) {
    int nabs = n0 + wn + ni * 16 + lr;
    vbr[ni] = br[nabs];
    vbi[ni] = bi[nabs];
  }

  // LDS-staged epilogue: full-line coalesced stores
  if (sec < 2) {
    unsigned short* dst = (sec == 0) ? q2 : k2;
#define QK_PASS(ACC, BV, POFF)                                                  \
    for (int ni = 0; ni < 4; ++ni)                                              \
      for (int mi = 0; mi < 4; ++mi)                                            \
        for (int r = 0; r < 4; ++r)                                             \
          sC[wm + mi * 16 + lk * 4 + r][wn + ni * 16 + lr] =                    \
              f2bf(ACC[mi][ni][r] + BV[ni]);                                    \
    __syncthreads();                                                            \
    for (int it = 0; it < 8; ++it) {                                            \
      int c = it * 256 + tid;                                                   \
      int m = c >> 4, sub = c & 15, h_i = sub >> 3, d8 = sub & 7;               \
      u16x8 v = *(const u16x8*)&sC[m][h_i * 64 + d8 * 8];                       \
      size_t addr = ((size_t)((bb * 16 + h_base + h_i) * 1024 + ss0 + m)) * 128 \
                    + POFF + d8 * 8;                                            \
      *(u16x8*)(dst + addr) = v;                                                \
    }                                                                           \
    __syncthreads();
    QK_PASS(accre, vbr, 0)
    QK_PASS(accim, vbi, 64)
#undef QK_PASS
  } else {
#define VT_PASS(ACC, BV, POFF)                                                  \
    for (int ni = 0; ni < 4; ++ni)                                              \
      for (int mi = 0; mi < 4; ++mi)                                            \
        for (int r = 0; r < 4; ++r)                                             \
          sCt[wn + ni * 16 + lr][wm + mi * 16 + lk * 4 + r] =                   \
              f2bf(ACC[mi][ni][r] + BV[ni]);                                    \
    __syncthreads();                                                            \
    for (int it = 0; it < 8; ++it) {                                            \
      int c = it * 256 + tid;                                                   \
      int nl = c >> 4, sub = c & 15;                                            \
      int h_i = nl >> 6, d = nl & 63;                                           \
      u16x8 v = *(const u16x8*)&sCt[nl][sub * 8];                               \
      size_t addr = ((size_t)(bb * 16 + h_base + h_i) * 128 + d + POFF) * 1024  \
                    + ss0 + sub * 8;                                            \
      *(u16x8*)(vt + addr) = v;                                                 \
    }                                                                           \
    __syncthreads();
    VT_PASS(accre, vbr, 0)
    VT_PASS(accim, vbi, 64)
#undef VT_PASS
  }
}

// ---------------------------------------------------------------- attention
// grid (128 bh, 16 qtiles), 256 thr = 4 waves x 16 q-rows, flash online softmax
__global__ __launch_bounds__(256, 2) void attn_kernel(
    const unsigned short* __restrict__ q2, const unsigned short* __restrict__ k2,
    const unsigned short* __restrict__ vt,
    unsigned short* __restrict__ aor, unsigned short* __restrict__ aoi) {
  __shared__ unsigned short sQ[64][128];
  __shared__ unsigned short sK[64][128];
  __shared__ unsigned short sV[128][64];
  __shared__ unsigned short sP[4][16][72];  // +8 pad -> conflict-free A reads

  const int tid = threadIdx.x, lane = tid & 63, w = tid >> 6;
  const int lr = lane & 15, lk = lane >> 4;
  const int bh = blockIdx.x;
  const int q0 = blockIdx.y * 64;
  const int bb = bh >> 4, hh = bh & 15;

  // stage Q tile (64 x 128) once
  const unsigned short* qbase = q2 + (size_t)bh * 131072 + (size_t)q0 * 128;
  for (int c = 0; c < 4; ++c) {
    int rb = (w * 4 + c) * 4;
    gload_lds16(qbase + (size_t)(rb + (lane >> 4)) * 128 + (lane & 15) * 8,
                &sQ[rb][0]);
  }

  f32x4 o[8];
  for (int i = 0; i < 8; ++i) o[i] = {0.f, 0.f, 0.f, 0.f};
  float mrun[4] = {-1e30f, -1e30f, -1e30f, -1e30f};
  float lrun[4] = {0.f, 0.f, 0.f, 0.f};
  const float SC = 0.125f;  // 1/sqrt(64)

  for (int t0 = 0; t0 < 1024; t0 += 64) {
    const unsigned short* kb = k2 + (size_t)bh * 131072 + (size_t)t0 * 128;
    for (int c = 0; c < 4; ++c) {
      int rb = (w * 4 + c) * 4;
      gload_lds16(kb + (size_t)(rb + (lane >> 4)) * 128 + (lane & 15) * 8,
                  &sK[rb][0]);
    }
    const unsigned short* vb = vt + (size_t)bh * 131072 + t0;
    for (int c = 0; c < 4; ++c) {
      int rb = (w * 4 + c) * 8;
      gload_lds16(vb + (size_t)(rb + (lane >> 3)) * 1024 + (lane & 7) * 8,
                  &sV[rb][0]);
    }
    __syncthreads();

    // scores tile: rows = wave's 16 q-rows, cols = 64 t
    f32x4 sc[4];
    for (int nj = 0; nj < 4; ++nj) sc[nj] = {0.f, 0.f, 0.f, 0.f};
    for (int ks = 0; ks < 4; ++ks) {
      u16x8 qf = *(const u16x8*)&sQ[w * 16 + lr][ks * 32 + lk * 8];
      for (int nj = 0; nj < 4; ++nj) {
        u16x8 kf = *(const u16x8*)&sK[nj * 16 + lr][ks * 32 + lk * 8];
        sc[nj] = mfma_bf16(qf, kf, sc[nj]);
      }
    }

    // online softmax (row r of this lane = 4*lk + r)
    for (int r = 0; r < 4; ++r) {
      float s0 = sc[0][r] * SC, s1 = sc[1][r] * SC;
      float s2 = sc[2][r] * SC, s3 = sc[3][r] * SC;
      float mx = fmaxf(fmaxf(s0, s1), fmaxf(s2, s3));
      for (int msk = 1; msk < 16; msk <<= 1) mx = fmaxf(mx, __shfl_xor(mx, msk));
      float mnew = fmaxf(mrun[r], mx);
      float corr = __expf(mrun[r] - mnew);
      float p0 = __expf(s0 - mnew), p1 = __expf(s1 - mnew);
      float p2 = __expf(s2 - mnew), p3 = __expf(s3 - mnew);
      float rs = p0 + p1 + p2 + p3;
      for (int msk = 1; msk < 16; msk <<= 1) rs += __shfl_xor(rs, msk);
      lrun[r] = lrun[r] * corr + rs;
      mrun[r] = mnew;
      for (int ni = 0; ni < 8; ++ni) o[ni][r] *= corr;
      int prow = lk * 4 + r;
      sP[w][prow][0 * 16 + lr] = f2bf(p0);
      sP[w][prow][1 * 16 + lr] = f2bf(p1);
      sP[w][prow][2 * 16 + lr] = f2bf(p2);
      sP[w][prow][3 * 16 + lr] = f2bf(p3);
    }

    // PV: O[s, dd] += P[s, t] * VT[dd, t]
    for (int ks = 0; ks < 2; ++ks) {
      u16x8 pf = *(const u16x8*)&sP[w][lr][ks * 32 + lk * 8];
      for (int ni = 0; ni < 8; ++ni) {
        u16x8 vf = *(const u16x8*)&sV[ni * 16 + lr][ks * 32 + lk * 8];
        o[ni] = mfma_bf16(pf, vf, o[ni]);
      }
    }
    __syncthreads();
  }

  for (int r = 0; r < 4; ++r) {
    float inv = 1.0f / lrun[r];
    for (int ni = 0; ni < 8; ++ni) o[ni][r] *= inv;
  }
  for (int ni = 0; ni < 8; ++ni) {
    int dd = ni * 16 + lr;
    for (int r = 0; r < 4; ++r) {
      int sg = q0 + w * 16 + lk * 4 + r;
      size_t tok = (size_t)sg * 8 + bb;
      if (dd < 64)
        aor[tok * 1024 + hh * 64 + dd] = f2bf(o[ni][r]);
      else
        aoi[tok * 1024 + hh * 64 + (dd - 64)] = f2bf(o[ni][r]);
    }
  }
}

// ---------------------------------------------------------------- out proj
__global__ __launch_bounds__(256, 2) void out_gemm(
    const unsigned short* __restrict__ ar, const unsigned short* __restrict__ ai,
    const unsigned short* __restrict__ wr, const unsigned short* __restrict__ wi,
    const float* __restrict__ br, const float* __restrict__ bi,
    float* __restrict__ out) {
  __shared__ unsigned short sA[2][128][32];
  __shared__ unsigned short sW[2][128][32];

  const int tid = threadIdx.x;
  const int lane = tid & 63;
  const int w = tid >> 6;
  const int lr = lane & 15, lk = lane >> 4;
  const int wm = (w & 1) * 64, wn = (w >> 1) * 64;
  const int m0 = blockIdx.x * 128;
  const int n0 = blockIdx.y * 128;

  f32x4 accre[4][4], accim[4][4];
  for (int i = 0; i < 4; ++i)
    for (int j = 0; j < 4; ++j) {
      accre[i][j] = {0.f, 0.f, 0.f, 0.f};
      accim[i][j] = {0.f, 0.f, 0.f, 0.f};
    }
  const u16x8 sign8 = {0x8000, 0x8000, 0x8000, 0x8000, 0x8000, 0x8000, 0x8000, 0x8000};

  for (int k0 = 0; k0 < 1024; k0 += 32) {
    for (int c = 0; c < 2; ++c) {
      int cw = w * 2 + c;
      int row = cw * 16 + (lane >> 2);
      int slot = lane & 3;
      size_t ga = (size_t)(m0 + row) * 1024 + k0 + slot * 8;
      size_t gw = (size_t)(n0 + row) * 1024 + k0 + slot * 8;
      gload_lds16(ar + ga, &sA[0][cw * 16][0]);
      gload_lds16(ai + ga, &sA[1][cw * 16][0]);
      gload_lds16(wr + gw, &sW[0][cw * 16][0]);
      gload_lds16(wi + gw, &sW[1][cw * 16][0]);
    }
    __syncthreads();

    u16x8 fWr[4], fWi[4];
    for (int ni = 0; ni < 4; ++ni) {
      fWr[ni] = *(const u16x8*)&sW[0][wn + ni * 16 + lr][lk * 8];
      fWi[ni] = *(const u16x8*)&sW[1][wn + ni * 16 + lr][lk * 8];
    }
    for (int mi = 0; mi < 4; ++mi) {
      u16x8 a_r = *(const u16x8*)&sA[0][wm + mi * 16 + lr][lk * 8];
      u16x8 a_i = *(const u16x8*)&sA[1][wm + mi * 16 + lr][lk * 8];
      u16x8 na_i = a_i ^ sign8;
      for (int ni = 0; ni < 4; ++ni) {
        accre[mi][ni] = mfma_bf16(a_r, fWr[ni], accre[mi][ni]);
        accre[mi][ni] = mfma_bf16(na_i, fWi[ni], accre[mi][ni]);
        accim[mi][ni] = mfma_bf16(a_r, fWi[ni], accim[mi][ni]);
        accim[mi][ni] = mfma_bf16(a_i, fWr[ni], accim[mi][ni]);
      }
    }
    __syncthreads();
  }

  for (int ni = 0; ni < 4; ++ni) {
    int n = n0 + wn + ni * 16 + lr;
    float vbr = br[n], vbi = bi[n];
    for (int mi = 0; mi < 4; ++mi) {
      for (int r = 0; r < 4; ++r) {
        int m = m0 + wm + mi * 16 + lk * 4 + r;
        out[(size_t)m * 1024 + n] = accre[mi][ni][r] + vbr;
        out[8388608 + (size_t)m * 1024 + n] = accim[mi][ni][r] + vbi;
      }
    }
  }
}

// ---------------------------------------------------------------- launch
extern "C" void kernel_launch(void* const* d_in, const int* in_sizes, int n_in,
                              void* d_out, int out_size, void* d_ws, size_t ws_size,
                              hipStream_t stream) {
  const float* qre = (const float*)d_in[0];
  const float* qim = (const float*)d_in[1];
  const float* kre = (const float*)d_in[2];
  const float* kim = (const float*)d_in[3];
  const float* vre = (const float*)d_in[4];
  const float* vim = (const float*)d_in[5];
  const float* wqkv_re = (const float*)d_in[6];
  const float* wqkv_im = (const float*)d_in[7];
  const float* bqr = (const float*)d_in[8];
  const float* bqi = (const float*)d_in[9];
  const float* wo_re = (const float*)d_in[10];
  const float* wo_im = (const float*)d_in[11];
  const float* bor = (const float*)d_in[12];
  const float* boi = (const float*)d_in[13];

  char* ws = (char*)d_ws;
  unsigned short* wr_bf  = (unsigned short*)(ws + 0);          //  6.29 MB
  unsigned short* wi_bf  = (unsigned short*)(ws + 6291456);    //  6.29 MB
  unsigned short* wor_bf = (unsigned short*)(ws + 12582912);   //  2.10 MB
  unsigned short* woi_bf = (unsigned short*)(ws + 14680064);   //  2.10 MB
  unsigned short* q2     = (unsigned short*)(ws + 16777216);   // 33.55 MB
  unsigned short* k2     = (unsigned short*)(ws + 50331648);   // 33.55 MB
  unsigned short* vt     = (unsigned short*)(ws + 83886080);   // 33.55 MB
  unsigned short* aor    = (unsigned short*)(ws + 117440512);  // 16.78 MB
  unsigned short* aoi    = (unsigned short*)(ws + 134217728);  // 16.78 MB (end 150.99 MB)

  cvt_kernel<<<3072, 256, 0, stream>>>(wqkv_re, wr_bf, 3145728);
  cvt_kernel<<<3072, 256, 0, stream>>>(wqkv_im, wi_bf, 3145728);
  cvt_kernel<<<1024, 256, 0, stream>>>(wo_re, wor_bf, 1048576);
  cvt_kernel<<<1024, 256, 0, stream>>>(wo_im, woi_bf, 1048576);

  proj_gemm<<<dim3(24, 64), 256, 0, stream>>>(qre, qim, kre, kim, vre, vim,
                                              wr_bf, wi_bf, bqr, bqi, q2, k2, vt);
  attn_kernel<<<dim3(128, 16), 256, 0, stream>>>(q2, k2, vt, aor, aoi);
  out_gemm<<<dim3(64, 8), 256, 0, stream>>>(aor, aoi, wor_bf, woi_bf, bor, boi,
                                            (float*)d_out);
}

// Round 3
// 539.530 us; speedup vs baseline: 3.0408x; 1.2454x over previous
//
#include <hip/hip_runtime.h>

// Problem constants: S=1024, B=8, E=1024, H=16, HD=64
#define M_TOK 8192   // S*B
#define SEQ   1024
#define NB    8
#define EMB   1024
#define NH    16

typedef float  f32x4 __attribute__((ext_vector_type(4)));
typedef __bf16 bf16x8 __attribute__((ext_vector_type(8)));
typedef unsigned short u16x8 __attribute__((ext_vector_type(8)));
typedef unsigned short u16x4 __attribute__((ext_vector_type(4)));

__device__ __forceinline__ unsigned short f2bf(float f) {
  unsigned int u = __builtin_bit_cast(unsigned int, f);
  return (unsigned short)((u + 0x7fffu + ((u >> 16) & 1u)) >> 16);
}

__device__ __forceinline__ f32x4 mfma_bf16(u16x8 a, u16x8 b, f32x4 c) {
  return __builtin_amdgcn_mfma_f32_16x16x32_bf16(
      __builtin_bit_cast(bf16x8, a), __builtin_bit_cast(bf16x8, b), c, 0, 0, 0);
}

__device__ __forceinline__ void gload_lds16(const void* g, void* l) {
  __builtin_amdgcn_global_load_lds(
      (const __attribute__((address_space(1))) void*)g,
      (__attribute__((address_space(3))) void*)l, 16, 0, 0);
}

// ---------------------------------------------------------------- converts
__global__ __launch_bounds__(256) void cvt_kernel(const float* __restrict__ src,
                                                  unsigned short* __restrict__ dst,
                                                  int n) {
  int i = (blockIdx.x * 256 + threadIdx.x) * 4;
  if (i >= n) return;
  float4 v = *reinterpret_cast<const float4*>(src + i);
  u16x4 o = {f2bf(v.x), f2bf(v.y), f2bf(v.z), f2bf(v.w)};
  *reinterpret_cast<u16x4*>(dst + i) = o;
}

// ---------------------------------------------------------------- QKV proj
// Per-batch m-tiles: block handles 128 consecutive s at fixed b.
// writes q2/k2: (B,H,S,128) bf16 (re|im on d axis), vt: (B,H,128,S) bf16
__global__ __launch_bounds__(256, 2) void proj_gemm(
    const float* __restrict__ qre, const float* __restrict__ qim,
    const float* __restrict__ kre, const float* __restrict__ kim,
    const float* __restrict__ vre, const float* __restrict__ vim,
    const unsigned short* __restrict__ wr, const unsigned short* __restrict__ wi,
    const float* __restrict__ br, const float* __restrict__ bi,
    unsigned short* __restrict__ q2, unsigned short* __restrict__ k2,
    unsigned short* __restrict__ vt) {
  // one aliased LDS pool: K-loop uses sA(re,im)+sW(re,im); epilogue reuses as sC/sCt
  __shared__ __align__(16) unsigned short smem[18432];  // 36864 B
  unsigned short (*sA0)[40] = (unsigned short (*)[40])(smem);            // [128][40]
  unsigned short (*sA1)[40] = (unsigned short (*)[40])(smem + 5120);
  unsigned short (*sW0)[32] = (unsigned short (*)[32])(smem + 10240);    // [128][32]
  unsigned short (*sW1)[32] = (unsigned short (*)[32])(smem + 14336);
  unsigned short (*sC)[140]  = (unsigned short (*)[140])(smem);          // m-major stage
  unsigned short (*sCt)[144] = (unsigned short (*)[144])(smem);         // n-major stage

  const int tid = threadIdx.x;
  const int lane = tid & 63;
  const int w = tid >> 6;
  const int lr = lane & 15, lk = lane >> 4;
  const int wm = (w & 1) * 64, wn = (w >> 1) * 64;
  const int n0 = blockIdx.x * 128;
  const int sec = n0 >> 10;
  const int bb = blockIdx.y & 7;
  const int ss0 = (blockIdx.y >> 3) * 128;
  const int h_base = (n0 & 1023) >> 6;

  const float* aRe = (sec == 0) ? qre : ((sec == 1) ? kre : vre);
  const float* aIm = (sec == 0) ? qim : ((sec == 1) ? kim : vim);

  const int srow = tid >> 1;   // 0..127 (local s)
  const int shalf = tid & 1;   // 0..1
  const size_t arow = (size_t)((ss0 + srow) * 8 + bb) * 1024 + shalf * 16;
  const float* gARe = aRe + arow;
  const float* gAIm = aIm + arow;

  f32x4 accre[4][4], accim[4][4];
  for (int i = 0; i < 4; ++i)
    for (int j = 0; j < 4; ++j) {
      accre[i][j] = {0.f, 0.f, 0.f, 0.f};
      accim[i][j] = {0.f, 0.f, 0.f, 0.f};
    }
  const u16x8 sign8 = {0x8000, 0x8000, 0x8000, 0x8000, 0x8000, 0x8000, 0x8000, 0x8000};

  for (int k0 = 0; k0 < 1024; k0 += 32) {
    // async W staging (bf16 already)
    for (int c = 0; c < 2; ++c) {
      int cw = w * 2 + c;
      int row = cw * 16 + (lane >> 2);
      int slot = lane & 3;
      size_t goff = (size_t)(n0 + row) * 1024 + k0 + slot * 8;
      gload_lds16(wr + goff, &sW0[cw * 16][0]);
      gload_lds16(wi + goff, &sW1[cw * 16][0]);
    }
    // reg-staged A with f32->bf16
    {
      float4 r0 = *(const float4*)(gARe + k0);
      float4 r1 = *(const float4*)(gARe + k0 + 4);
      float4 r2 = *(const float4*)(gARe + k0 + 8);
      float4 r3 = *(const float4*)(gARe + k0 + 12);
      u16x8 p0 = {f2bf(r0.x), f2bf(r0.y), f2bf(r0.z), f2bf(r0.w),
                  f2bf(r1.x), f2bf(r1.y), f2bf(r1.z), f2bf(r1.w)};
      u16x8 p1 = {f2bf(r2.x), f2bf(r2.y), f2bf(r2.z), f2bf(r2.w),
                  f2bf(r3.x), f2bf(r3.y), f2bf(r3.z), f2bf(r3.w)};
      *(u16x8*)&sA0[srow][shalf * 16] = p0;
      *(u16x8*)&sA0[srow][shalf * 16 + 8] = p1;
      float4 i0 = *(const float4*)(gAIm + k0);
      float4 i1 = *(const float4*)(gAIm + k0 + 4);
      float4 i2 = *(const float4*)(gAIm + k0 + 8);
      float4 i3 = *(const float4*)(gAIm + k0 + 12);
      u16x8 p2 = {f2bf(i0.x), f2bf(i0.y), f2bf(i0.z), f2bf(i0.w),
                  f2bf(i1.x), f2bf(i1.y), f2bf(i1.z), f2bf(i1.w)};
      u16x8 p3 = {f2bf(i2.x), f2bf(i2.y), f2bf(i2.z), f2bf(i2.w),
                  f2bf(i3.x), f2bf(i3.y), f2bf(i3.z), f2bf(i3.w)};
      *(u16x8*)&sA1[srow][shalf * 16] = p2;
      *(u16x8*)&sA1[srow][shalf * 16 + 8] = p3;
    }
    __syncthreads();

    u16x8 fWr[4], fWi[4];
    for (int ni = 0; ni < 4; ++ni) {
      fWr[ni] = *(const u16x8*)&sW0[wn + ni * 16 + lr][lk * 8];
      fWi[ni] = *(const u16x8*)&sW1[wn + ni * 16 + lr][lk * 8];
    }
    for (int mi = 0; mi < 4; ++mi) {
      u16x8 ar = *(const u16x8*)&sA0[wm + mi * 16 + lr][lk * 8];
      u16x8 ai = *(const u16x8*)&sA1[wm + mi * 16 + lr][lk * 8];
      u16x8 nai = ai ^ sign8;
      for (int ni = 0; ni < 4; ++ni) {
        accre[mi][ni] = mfma_bf16(ar, fWr[ni], accre[mi][ni]);
        accre[mi][ni] = mfma_bf16(nai, fWi[ni], accre[mi][ni]);
        accim[mi][ni] = mfma_bf16(ar, fWi[ni], accim[mi][ni]);
        accim[mi][ni] = mfma_bf16(ai, fWr[ni], accim[mi][ni]);
      }
    }
    __syncthreads();
  }

  // bias values per lane-column
  float vbr[4], vbi[4];
  for (int ni = 0; ni < 4; ++ni) {
    int nabs = n0 + wn + ni * 16 + lr;
    vbr[ni] = br[nabs];
    vbi[ni] = bi[nabs];
  }

  // LDS-staged epilogue: full-line coalesced stores
  if (sec < 2) {
    unsigned short* dst = (sec == 0) ? q2 : k2;
#define QK_PASS(ACC, BV, POFF)                                                  \
    for (int ni = 0; ni < 4; ++ni)                                              \
      for (int mi = 0; mi < 4; ++mi)                                            \
        for (int r = 0; r < 4; ++r)                                             \
          sC[wm + mi * 16 + lk * 4 + r][wn + ni * 16 + lr] =                    \
              f2bf(ACC[mi][ni][r] + BV[ni]);                                    \
    __syncthreads();                                                            \
    for (int it = 0; it < 8; ++it) {                                            \
      int c = it * 256 + tid;                                                   \
      int m = c >> 4, sub = c & 15, h_i = sub >> 3, d8 = sub & 7;               \
      u16x8 v = *(const u16x8*)&sC[m][h_i * 64 + d8 * 8];                       \
      size_t addr = ((size_t)((bb * 16 + h_base + h_i) * 1024 + ss0 + m)) * 128 \
                    + POFF + d8 * 8;                                            \
      *(u16x8*)(dst + addr) = v;                                                \
    }                                                                           \
    __syncthreads();
    QK_PASS(accre, vbr, 0)
    QK_PASS(accim, vbi, 64)
#undef QK_PASS
  } else {
#define VT_PASS(ACC, BV, POFF)                                                  \
    for (int ni = 0; ni < 4; ++ni)                                              \
      for (int mi = 0; mi < 4; ++mi)                                            \
        for (int r = 0; r < 4; ++r)                                             \
          sCt[wn + ni * 16 + lr][wm + mi * 16 + lk * 4 + r] =                   \
              f2bf(ACC[mi][ni][r] + BV[ni]);                                    \
    __syncthreads();                                                            \
    for (int it = 0; it < 8; ++it) {                                            \
      int c = it * 256 + tid;                                                   \
      int nl = c >> 4, sub = c & 15;                                            \
      int h_i = nl >> 6, d = nl & 63;                                           \
      u16x8 v = *(const u16x8*)&sCt[nl][sub * 8];                               \
      size_t addr = ((size_t)(bb * 16 + h_base + h_i) * 128 + d + POFF) * 1024  \
                    + ss0 + sub * 8;                                            \
      *(u16x8*)(vt + addr) = v;                                                 \
    }                                                                           \
    __syncthreads();
    VT_PASS(accre, vbr, 0)
    VT_PASS(accim, vbi, 64)
#undef VT_PASS
  }
}

// ---------------------------------------------------------------- attention
// grid (128 bh, 16 qtiles), 256 thr = 4 waves x 16 q-rows, flash online softmax
// LDS tiles XOR-swizzled (16B granule ^= row&7) via pre-swizzled global source
// (rule #21: linear gload_lds dest + inverse-swizzled source + swizzled read)
__global__ __launch_bounds__(256, 2) void attn_kernel(
    const unsigned short* __restrict__ q2, const unsigned short* __restrict__ k2,
    const unsigned short* __restrict__ vt,
    unsigned short* __restrict__ aor, unsigned short* __restrict__ aoi) {
  __shared__ unsigned short sQ[64][128];
  __shared__ unsigned short sK[64][128];
  __shared__ unsigned short sV[128][64];
  __shared__ unsigned short sP[4][16][72];  // +8 pad -> ~2-way

  const int tid = threadIdx.x, lane = tid & 63, w = tid >> 6;
  const int lr = lane & 15, lk = lane >> 4;
  const int bh = blockIdx.x;
  const int q0 = blockIdx.y * 64;
  const int bb = bh >> 4, hh = bh & 15;

  // stage Q tile (64 x 128) once, swizzled source
  const unsigned short* qbase = q2 + (size_t)bh * 131072 + (size_t)q0 * 128;
  for (int c = 0; c < 4; ++c) {
    int rb = (w * 4 + c) * 4;
    int row = rb + (lane >> 4);
    int blk = (lane & 15) ^ (row & 7);
    gload_lds16(qbase + (size_t)row * 128 + blk * 8, &sQ[rb][0]);
  }

  f32x4 o[8];
  for (int i = 0; i < 8; ++i) o[i] = {0.f, 0.f, 0.f, 0.f};
  float mrun[4] = {-1e30f, -1e30f, -1e30f, -1e30f};
  float lrun[4] = {0.f, 0.f, 0.f, 0.f};
  const float SC = 0.125f;  // 1/sqrt(64)

  const int qrow = w * 16 + lr;
  const int qsw = qrow & 7;

  for (int t0 = 0; t0 < 1024; t0 += 64) {
    const unsigned short* kb = k2 + (size_t)bh * 131072 + (size_t)t0 * 128;
    for (int c = 0; c < 4; ++c) {
      int rb = (w * 4 + c) * 4;
      int row = rb + (lane >> 4);
      int blk = (lane & 15) ^ (row & 7);
      gload_lds16(kb + (size_t)row * 128 + blk * 8, &sK[rb][0]);
    }
    const unsigned short* vb = vt + (size_t)bh * 131072 + t0;
    for (int c = 0; c < 4; ++c) {
      int rb = (w * 4 + c) * 8;
      int row = rb + (lane >> 3);
      int blk = (lane & 7) ^ (row & 7);
      gload_lds16(vb + (size_t)row * 1024 + blk * 8, &sV[rb][0]);
    }
    __syncthreads();

    // scores tile: rows = wave's 16 q-rows, cols = 64 t
    f32x4 sc[4];
    for (int nj = 0; nj < 4; ++nj) sc[nj] = {0.f, 0.f, 0.f, 0.f};
    for (int ks = 0; ks < 4; ++ks) {
      u16x8 qf = *(const u16x8*)&sQ[qrow][((ks * 4 + lk) ^ qsw) * 8];
      for (int nj = 0; nj < 4; ++nj) {
        int krow = nj * 16 + lr;
        u16x8 kf = *(const u16x8*)&sK[krow][((ks * 4 + lk) ^ (krow & 7)) * 8];
        sc[nj] = mfma_bf16(qf, kf, sc[nj]);
      }
    }

    // online softmax (row r of this lane = 4*lk + r)
    for (int r = 0; r < 4; ++r) {
      float s0 = sc[0][r] * SC, s1 = sc[1][r] * SC;
      float s2 = sc[2][r] * SC, s3 = sc[3][r] * SC;
      float mx = fmaxf(fmaxf(s0, s1), fmaxf(s2, s3));
      for (int msk = 1; msk < 16; msk <<= 1) mx = fmaxf(mx, __shfl_xor(mx, msk));
      float mnew = fmaxf(mrun[r], mx);
      float corr = __expf(mrun[r] - mnew);
      float p0 = __expf(s0 - mnew), p1 = __expf(s1 - mnew);
      float p2 = __expf(s2 - mnew), p3 = __expf(s3 - mnew);
      float rs = p0 + p1 + p2 + p3;
      for (int msk = 1; msk < 16; msk <<= 1) rs += __shfl_xor(rs, msk);
      lrun[r] = lrun[r] * corr + rs;
      mrun[r] = mnew;
      for (int ni = 0; ni < 8; ++ni) o[ni][r] *= corr;
      int prow = lk * 4 + r;
      sP[w][prow][0 * 16 + lr] = f2bf(p0);
      sP[w][prow][1 * 16 + lr] = f2bf(p1);
      sP[w][prow][2 * 16 + lr] = f2bf(p2);
      sP[w][prow][3 * 16 + lr] = f2bf(p3);
    }

    // PV: O[s, dd] += P[s, t] * VT[dd, t]
    for (int ks = 0; ks < 2; ++ks) {
      u16x8 pf = *(const u16x8*)&sP[w][lr][ks * 32 + lk * 8];
      for (int ni = 0; ni < 8; ++ni) {
        int vrow = ni * 16 + lr;
        u16x8 vf = *(const u16x8*)&sV[vrow][((ks * 4 + lk) ^ (vrow & 7)) * 8];
        o[ni] = mfma_bf16(pf, vf, o[ni]);
      }
    }
    __syncthreads();
  }

  for (int r = 0; r < 4; ++r) {
    float inv = 1.0f / lrun[r];
    for (int ni = 0; ni < 8; ++ni) o[ni][r] *= inv;
  }
  for (int ni = 0; ni < 8; ++ni) {
    int dd = ni * 16 + lr;
    for (int r = 0; r < 4; ++r) {
      int sg = q0 + w * 16 + lk * 4 + r;
      size_t tok = (size_t)sg * 8 + bb;
      if (dd < 64)
        aor[tok * 1024 + hh * 64 + dd] = f2bf(o[ni][r]);
      else
        aoi[tok * 1024 + hh * 64 + (dd - 64)] = f2bf(o[ni][r]);
    }
  }
}

// ---------------------------------------------------------------- out proj
__global__ __launch_bounds__(256, 2) void out_gemm(
    const unsigned short* __restrict__ ar, const unsigned short* __restrict__ ai,
    const unsigned short* __restrict__ wr, const unsigned short* __restrict__ wi,
    const float* __restrict__ br, const float* __restrict__ bi,
    float* __restrict__ out) {
  __shared__ unsigned short sA[2][128][32];
  __shared__ unsigned short sW[2][128][32];

  const int tid = threadIdx.x;
  const int lane = tid & 63;
  const int w = tid >> 6;
  const int lr = lane & 15, lk = lane >> 4;
  const int wm = (w & 1) * 64, wn = (w >> 1) * 64;
  const int m0 = blockIdx.x * 128;
  const int n0 = blockIdx.y * 128;

  f32x4 accre[4][4], accim[4][4];
  for (int i = 0; i < 4; ++i)
    for (int j = 0; j < 4; ++j) {
      accre[i][j] = {0.f, 0.f, 0.f, 0.f};
      accim[i][j] = {0.f, 0.f, 0.f, 0.f};
    }
  const u16x8 sign8 = {0x8000, 0x8000, 0x8000, 0x8000, 0x8000, 0x8000, 0x8000, 0x8000};

  for (int k0 = 0; k0 < 1024; k0 += 32) {
    for (int c = 0; c < 2; ++c) {
      int cw = w * 2 + c;
      int row = cw * 16 + (lane >> 2);
      int slot = lane & 3;
      size_t ga = (size_t)(m0 + row) * 1024 + k0 + slot * 8;
      size_t gw = (size_t)(n0 + row) * 1024 + k0 + slot * 8;
      gload_lds16(ar + ga, &sA[0][cw * 16][0]);
      gload_lds16(ai + ga, &sA[1][cw * 16][0]);
      gload_lds16(wr + gw, &sW[0][cw * 16][0]);
      gload_lds16(wi + gw, &sW[1][cw * 16][0]);
    }
    __syncthreads();

    u16x8 fWr[4], fWi[4];
    for (int ni = 0; ni < 4; ++ni) {
      fWr[ni] = *(const u16x8*)&sW[0][wn + ni * 16 + lr][lk * 8];
      fWi[ni] = *(const u16x8*)&sW[1][wn + ni * 16 + lr][lk * 8];
    }
    for (int mi = 0; mi < 4; ++mi) {
      u16x8 a_r = *(const u16x8*)&sA[0][wm + mi * 16 + lr][lk * 8];
      u16x8 a_i = *(const u16x8*)&sA[1][wm + mi * 16 + lr][lk * 8];
      u16x8 na_i = a_i ^ sign8;
      for (int ni = 0; ni < 4; ++ni) {
        accre[mi][ni] = mfma_bf16(a_r, fWr[ni], accre[mi][ni]);
        accre[mi][ni] = mfma_bf16(na_i, fWi[ni], accre[mi][ni]);
        accim[mi][ni] = mfma_bf16(a_r, fWi[ni], accim[mi][ni]);
        accim[mi][ni] = mfma_bf16(a_i, fWr[ni], accim[mi][ni]);
      }
    }
    __syncthreads();
  }

  for (int ni = 0; ni < 4; ++ni) {
    int n = n0 + wn + ni * 16 + lr;
    float vbr = br[n], vbi = bi[n];
    for (int mi = 0; mi < 4; ++mi) {
      for (int r = 0; r < 4; ++r) {
        int m = m0 + wm + mi * 16 + lk * 4 + r;
        out[(size_t)m * 1024 + n] = accre[mi][ni][r] + vbr;
        out[8388608 + (size_t)m * 1024 + n] = accim[mi][ni][r] + vbi;
      }
    }
  }
}

// ---------------------------------------------------------------- launch
extern "C" void kernel_launch(void* const* d_in, const int* in_sizes, int n_in,
                              void* d_out, int out_size, void* d_ws, size_t ws_size,
                              hipStream_t stream) {
  const float* qre = (const float*)d_in[0];
  const float* qim = (const float*)d_in[1];
  const float* kre = (const float*)d_in[2];
  const float* kim = (const float*)d_in[3];
  const float* vre = (const float*)d_in[4];
  const float* vim = (const float*)d_in[5];
  const float* wqkv_re = (const float*)d_in[6];
  const float* wqkv_im = (const float*)d_in[7];
  const float* bqr = (const float*)d_in[8];
  const float* bqi = (const float*)d_in[9];
  const float* wo_re = (const float*)d_in[10];
  const float* wo_im = (const float*)d_in[11];
  const float* bor = (const float*)d_in[12];
  const float* boi = (const float*)d_in[13];

  char* ws = (char*)d_ws;
  unsigned short* wr_bf  = (unsigned short*)(ws + 0);          //  6.29 MB
  unsigned short* wi_bf  = (unsigned short*)(ws + 6291456);    //  6.29 MB
  unsigned short* wor_bf = (unsigned short*)(ws + 12582912);   //  2.10 MB
  unsigned short* woi_bf = (unsigned short*)(ws + 14680064);   //  2.10 MB
  unsigned short* q2     = (unsigned short*)(ws + 16777216);   // 33.55 MB
  unsigned short* k2     = (unsigned short*)(ws + 50331648);   // 33.55 MB
  unsigned short* vt     = (unsigned short*)(ws + 83886080);   // 33.55 MB
  unsigned short* aor    = (unsigned short*)(ws + 117440512);  // 16.78 MB
  unsigned short* aoi    = (unsigned short*)(ws + 134217728);  // 16.78 MB (end 150.99 MB)

  cvt_kernel<<<3072, 256, 0, stream>>>(wqkv_re, wr_bf, 3145728);
  cvt_kernel<<<3072, 256, 0, stream>>>(wqkv_im, wi_bf, 3145728);
  cvt_kernel<<<1024, 256, 0, stream>>>(wo_re, wor_bf, 1048576);
  cvt_kernel<<<1024, 256, 0, stream>>>(wo_im, woi_bf, 1048576);

  proj_gemm<<<dim3(24, 64), 256, 0, stream>>>(qre, qim, kre, kim, vre, vim,
                                              wr_bf, wi_bf, bqr, bqi, q2, k2, vt);
  attn_kernel<<<dim3(128, 16), 256, 0, stream>>>(q2, k2, vt, aor, aoi);
  out_gemm<<<dim3(64, 8), 256, 0, stream>>>(aor, aoi, wor_bf, woi_bf, bor, boi,
                                            (float*)d_out);
}

// Round 4
// 502.627 us; speedup vs baseline: 3.2641x; 1.0734x over previous
//
#include <hip/hip_runtime.h>

// Problem constants: S=1024, B=8, E=1024, H=16, HD=64
#define M_TOK 8192   // S*B
#define SEQ   1024
#define NB    8
#define EMB   1024
#define NH    16

typedef float  f32x4 __attribute__((ext_vector_type(4)));
typedef __bf16 bf16x8 __attribute__((ext_vector_type(8)));
typedef unsigned short u16x8 __attribute__((ext_vector_type(8)));
typedef unsigned short u16x4 __attribute__((ext_vector_type(4)));

__device__ __forceinline__ unsigned short f2bf(float f) {
  unsigned int u = __builtin_bit_cast(unsigned int, f);
  return (unsigned short)((u + 0x7fffu + ((u >> 16) & 1u)) >> 16);
}

__device__ __forceinline__ f32x4 mfma_bf16(u16x8 a, u16x8 b, f32x4 c) {
  return __builtin_amdgcn_mfma_f32_16x16x32_bf16(
      __builtin_bit_cast(bf16x8, a), __builtin_bit_cast(bf16x8, b), c, 0, 0, 0);
}

__device__ __forceinline__ void gload_lds16(const void* g, void* l) {
  __builtin_amdgcn_global_load_lds(
      (const __attribute__((address_space(1))) void*)g,
      (__attribute__((address_space(3))) void*)l, 16, 0, 0);
}

// ---------------------------------------------------------------- converts
__global__ __launch_bounds__(256) void cvt_kernel(const float* __restrict__ src,
                                                  unsigned short* __restrict__ dst,
                                                  int n) {
  int i = (blockIdx.x * 256 + threadIdx.x) * 4;
  if (i >= n) return;
  float4 v = *reinterpret_cast<const float4*>(src + i);
  u16x4 o = {f2bf(v.x), f2bf(v.y), f2bf(v.z), f2bf(v.w)};
  *reinterpret_cast<u16x4*>(dst + i) = o;
}

// batched activation convert: 6 tensors of 8388608 f32, grid (8192, 6)
__global__ __launch_bounds__(256) void cvt6_kernel(
    const float* __restrict__ s0, const float* __restrict__ s1,
    const float* __restrict__ s2, const float* __restrict__ s3,
    const float* __restrict__ s4, const float* __restrict__ s5,
    unsigned short* __restrict__ d0, unsigned short* __restrict__ d1,
    unsigned short* __restrict__ d2, unsigned short* __restrict__ d3,
    unsigned short* __restrict__ d4, unsigned short* __restrict__ d5) {
  int which = blockIdx.y;
  const float* src = (which == 0) ? s0 : (which == 1) ? s1 : (which == 2) ? s2
                     : (which == 3) ? s3 : (which == 4) ? s4 : s5;
  unsigned short* dst = (which == 0) ? d0 : (which == 1) ? d1 : (which == 2) ? d2
                        : (which == 3) ? d3 : (which == 4) ? d4 : d5;
  int i = (blockIdx.x * 256 + threadIdx.x) * 4;
  float4 v = *reinterpret_cast<const float4*>(src + i);
  u16x4 o = {f2bf(v.x), f2bf(v.y), f2bf(v.z), f2bf(v.w)};
  *reinterpret_cast<u16x4*>(dst + i) = o;
}

// ---------------------------------------------------------------- QKV proj
// A preconverted bf16. Combined [128][re32|im32] XOR-swizzled tiles for A and W.
// Per-batch m-tiles; XCD-aware work swizzle (1536 = 8 x 192).
// writes q2/k2: (B,H,S,128) bf16 (re|im on d axis), vt: (B,H,128,S) bf16
__global__ __launch_bounds__(256, 2) void proj_gemm(
    const unsigned short* __restrict__ qreb, const unsigned short* __restrict__ qimb,
    const unsigned short* __restrict__ kreb, const unsigned short* __restrict__ kimb,
    const unsigned short* __restrict__ vreb, const unsigned short* __restrict__ vimb,
    const unsigned short* __restrict__ wr, const unsigned short* __restrict__ wi,
    const float* __restrict__ br, const float* __restrict__ bi,
    unsigned short* __restrict__ q2, unsigned short* __restrict__ k2,
    unsigned short* __restrict__ vt) {
  __shared__ __align__(16) unsigned short smem[18432];  // 36864 B
  unsigned short (*sA)[64] = (unsigned short (*)[64])(smem);          // [128][64]
  unsigned short (*sW)[64] = (unsigned short (*)[64])(smem + 8192);   // [128][64]
  unsigned short (*sC)[140]  = (unsigned short (*)[140])(smem);       // epilogue m-major
  unsigned short (*sCt)[144] = (unsigned short (*)[144])(smem);       // epilogue n-major

  const int tid = threadIdx.x;
  const int lane = tid & 63;
  const int w = tid >> 6;
  const int lr = lane & 15, lk = lane >> 4;
  const int wm = (w & 1) * 64, wn = (w >> 1) * 64;

  // XCD-aware bijective work swizzle: 1536 blocks = 8 XCD x 192
  const int lin = blockIdx.x + blockIdx.y * 24;
  const int wg = (lin & 7) * 192 + (lin >> 3);
  const int n0 = (wg % 24) * 128;
  const int mt = wg / 24;
  const int sec = n0 >> 10;
  const int bb = mt & 7;
  const int ss0 = (mt >> 3) * 128;
  const int h_base = (n0 & 1023) >> 6;

  const unsigned short* aRe = (sec == 0) ? qreb : ((sec == 1) ? kreb : vreb);
  const unsigned short* aIm = (sec == 0) ? qimb : ((sec == 1) ? kimb : vimb);

  // staging indices (constant over K): granule gid = c*256 + tid
  // row = gid>>3 (0..127), g = gid&7, source granule gsw = g ^ (row&7)
  int srow[4], sgsw[4];
  for (int c = 0; c < 4; ++c) {
    int gid = c * 256 + tid;
    srow[c] = gid >> 3;
    sgsw[c] = (gid & 7) ^ (srow[c] & 7);
  }

  f32x4 accre[4][4], accim[4][4];
  for (int i = 0; i < 4; ++i)
    for (int j = 0; j < 4; ++j) {
      accre[i][j] = {0.f, 0.f, 0.f, 0.f};
      accim[i][j] = {0.f, 0.f, 0.f, 0.f};
    }
  const u16x8 sign8 = {0x8000, 0x8000, 0x8000, 0x8000, 0x8000, 0x8000, 0x8000, 0x8000};

  for (int k0 = 0; k0 < 1024; k0 += 32) {
    for (int c = 0; c < 4; ++c) {
      int row = srow[c], gsw = sgsw[c];
      int kcol = k0 + (gsw & 3) * 8;
      // A: token row m = (ss0+row)*8 + bb
      size_t aoff = (size_t)((ss0 + row) * 8 + bb) * 1024 + kcol;
      gload_lds16((gsw < 4 ? aRe : aIm) + aoff, smem + (c * 256 + w * 64) * 8);
      // W: row n0+row
      size_t woff = (size_t)(n0 + row) * 1024 + kcol;
      gload_lds16((gsw < 4 ? wr : wi) + woff, smem + 8192 + (c * 256 + w * 64) * 8);
    }
    __syncthreads();

    u16x8 fWr[4], fWi[4];
    for (int ni = 0; ni < 4; ++ni) {
      int R = wn + ni * 16 + lr, sw = R & 7;
      fWr[ni] = *(const u16x8*)&sW[R][(lk ^ sw) * 8];
      fWi[ni] = *(const u16x8*)&sW[R][((4 + lk) ^ sw) * 8];
    }
    for (int mi = 0; mi < 4; ++mi) {
      int R = wm + mi * 16 + lr, sw = R & 7;
      u16x8 ar = *(const u16x8*)&sA[R][(lk ^ sw) * 8];
      u16x8 ai = *(const u16x8*)&sA[R][((4 + lk) ^ sw) * 8];
      u16x8 nai = ai ^ sign8;
      for (int ni = 0; ni < 4; ++ni) {
        accre[mi][ni] = mfma_bf16(ar, fWr[ni], accre[mi][ni]);
        accre[mi][ni] = mfma_bf16(nai, fWi[ni], accre[mi][ni]);
        accim[mi][ni] = mfma_bf16(ar, fWi[ni], accim[mi][ni]);
        accim[mi][ni] = mfma_bf16(ai, fWr[ni], accim[mi][ni]);
      }
    }
    __syncthreads();
  }

  // bias values per lane-column
  float vbr[4], vbi[4];
  for (int ni = 0; ni < 4; ++ni) {
    int nabs = n0 + wn + ni * 16 + lr;
    vbr[ni] = br[nabs];
    vbi[ni] = bi[nabs];
  }

  // LDS-staged epilogue: full-line coalesced stores
  if (sec < 2) {
    unsigned short* dst = (sec == 0) ? q2 : k2;
#define QK_PASS(ACC, BV, POFF)                                                  \
    for (int ni = 0; ni < 4; ++ni)                                              \
      for (int mi = 0; mi < 4; ++mi)                                            \
        for (int r = 0; r < 4; ++r)                                             \
          sC[wm + mi * 16 + lk * 4 + r][wn + ni * 16 + lr] =                    \
              f2bf(ACC[mi][ni][r] + BV[ni]);                                    \
    __syncthreads();                                                            \
    for (int it = 0; it < 8; ++it) {                                            \
      int c = it * 256 + tid;                                                   \
      int m = c >> 4, sub = c & 15, h_i = sub >> 3, d8 = sub & 7;               \
      u16x8 v = *(const u16x8*)&sC[m][h_i * 64 + d8 * 8];                       \
      size_t addr = ((size_t)((bb * 16 + h_base + h_i) * 1024 + ss0 + m)) * 128 \
                    + POFF + d8 * 8;                                            \
      *(u16x8*)(dst + addr) = v;                                                \
    }                                                                           \
    __syncthreads();
    QK_PASS(accre, vbr, 0)
    QK_PASS(accim, vbi, 64)
#undef QK_PASS
  } else {
#define VT_PASS(ACC, BV, POFF)                                                  \
    for (int ni = 0; ni < 4; ++ni)                                              \
      for (int mi = 0; mi < 4; ++mi)                                            \
        for (int r = 0; r < 4; ++r)                                             \
          sCt[wn + ni * 16 + lr][wm + mi * 16 + lk * 4 + r] =                   \
              f2bf(ACC[mi][ni][r] + BV[ni]);                                    \
    __syncthreads();                                                            \
    for (int it = 0; it < 8; ++it) {                                            \
      int c = it * 256 + tid;                                                   \
      int nl = c >> 4, sub = c & 15;                                            \
      int h_i = nl >> 6, d = nl & 63;                                           \
      u16x8 v = *(const u16x8*)&sCt[nl][sub * 8];                               \
      size_t addr = ((size_t)(bb * 16 + h_base + h_i) * 128 + d + POFF) * 1024  \
                    + ss0 + sub * 8;                                            \
      *(u16x8*)(vt + addr) = v;                                                 \
    }                                                                           \
    __syncthreads();
    VT_PASS(accre, vbr, 0)
    VT_PASS(accim, vbi, 64)
#undef VT_PASS
  }
}

// ---------------------------------------------------------------- attention
// grid (128 bh, 16 qtiles), 256 thr = 4 waves x 16 q-rows, flash online softmax
// LDS tiles XOR-swizzled (16B granule ^= row&7) via pre-swizzled global source
__global__ __launch_bounds__(256, 2) void attn_kernel(
    const unsigned short* __restrict__ q2, const unsigned short* __restrict__ k2,
    const unsigned short* __restrict__ vt,
    unsigned short* __restrict__ aor, unsigned short* __restrict__ aoi) {
  __shared__ unsigned short sQ[64][128];
  __shared__ unsigned short sK[64][128];
  __shared__ unsigned short sV[128][64];
  __shared__ unsigned short sP[4][16][72];  // +8 pad -> ~2-way

  const int tid = threadIdx.x, lane = tid & 63, w = tid >> 6;
  const int lr = lane & 15, lk = lane >> 4;
  const int bh = blockIdx.x;
  const int q0 = blockIdx.y * 64;
  const int bb = bh >> 4, hh = bh & 15;

  // stage Q tile (64 x 128) once, swizzled source
  const unsigned short* qbase = q2 + (size_t)bh * 131072 + (size_t)q0 * 128;
  for (int c = 0; c < 4; ++c) {
    int rb = (w * 4 + c) * 4;
    int row = rb + (lane >> 4);
    int blk = (lane & 15) ^ (row & 7);
    gload_lds16(qbase + (size_t)row * 128 + blk * 8, &sQ[rb][0]);
  }

  f32x4 o[8];
  for (int i = 0; i < 8; ++i) o[i] = {0.f, 0.f, 0.f, 0.f};
  float mrun[4] = {-1e30f, -1e30f, -1e30f, -1e30f};
  float lrun[4] = {0.f, 0.f, 0.f, 0.f};
  const float SC = 0.125f;  // 1/sqrt(64)

  const int qrow = w * 16 + lr;
  const int qsw = qrow & 7;

  for (int t0 = 0; t0 < 1024; t0 += 64) {
    const unsigned short* kb = k2 + (size_t)bh * 131072 + (size_t)t0 * 128;
    for (int c = 0; c < 4; ++c) {
      int rb = (w * 4 + c) * 4;
      int row = rb + (lane >> 4);
      int blk = (lane & 15) ^ (row & 7);
      gload_lds16(kb + (size_t)row * 128 + blk * 8, &sK[rb][0]);
    }
    const unsigned short* vb = vt + (size_t)bh * 131072 + t0;
    for (int c = 0; c < 4; ++c) {
      int rb = (w * 4 + c) * 8;
      int row = rb + (lane >> 3);
      int blk = (lane & 7) ^ (row & 7);
      gload_lds16(vb + (size_t)row * 1024 + blk * 8, &sV[rb][0]);
    }
    __syncthreads();

    // scores tile: rows = wave's 16 q-rows, cols = 64 t
    f32x4 sc[4];
    for (int nj = 0; nj < 4; ++nj) sc[nj] = {0.f, 0.f, 0.f, 0.f};
    for (int ks = 0; ks < 4; ++ks) {
      u16x8 qf = *(const u16x8*)&sQ[qrow][((ks * 4 + lk) ^ qsw) * 8];
      for (int nj = 0; nj < 4; ++nj) {
        int krow = nj * 16 + lr;
        u16x8 kf = *(const u16x8*)&sK[krow][((ks * 4 + lk) ^ (krow & 7)) * 8];
        sc[nj] = mfma_bf16(qf, kf, sc[nj]);
      }
    }

    // online softmax (row r of this lane = 4*lk + r)
    for (int r = 0; r < 4; ++r) {
      float s0 = sc[0][r] * SC, s1 = sc[1][r] * SC;
      float s2 = sc[2][r] * SC, s3 = sc[3][r] * SC;
      float mx = fmaxf(fmaxf(s0, s1), fmaxf(s2, s3));
      for (int msk = 1; msk < 16; msk <<= 1) mx = fmaxf(mx, __shfl_xor(mx, msk));
      float mnew = fmaxf(mrun[r], mx);
      float corr = __expf(mrun[r] - mnew);
      float p0 = __expf(s0 - mnew), p1 = __expf(s1 - mnew);
      float p2 = __expf(s2 - mnew), p3 = __expf(s3 - mnew);
      float rs = p0 + p1 + p2 + p3;
      for (int msk = 1; msk < 16; msk <<= 1) rs += __shfl_xor(rs, msk);
      lrun[r] = lrun[r] * corr + rs;
      mrun[r] = mnew;
      for (int ni = 0; ni < 8; ++ni) o[ni][r] *= corr;
      int prow = lk * 4 + r;
      sP[w][prow][0 * 16 + lr] = f2bf(p0);
      sP[w][prow][1 * 16 + lr] = f2bf(p1);
      sP[w][prow][2 * 16 + lr] = f2bf(p2);
      sP[w][prow][3 * 16 + lr] = f2bf(p3);
    }

    // PV: O[s, dd] += P[s, t] * VT[dd, t]
    for (int ks = 0; ks < 2; ++ks) {
      u16x8 pf = *(const u16x8*)&sP[w][lr][ks * 32 + lk * 8];
      for (int ni = 0; ni < 8; ++ni) {
        int vrow = ni * 16 + lr;
        u16x8 vf = *(const u16x8*)&sV[vrow][((ks * 4 + lk) ^ (vrow & 7)) * 8];
        o[ni] = mfma_bf16(pf, vf, o[ni]);
      }
    }
    __syncthreads();
  }

  for (int r = 0; r < 4; ++r) {
    float inv = 1.0f / lrun[r];
    for (int ni = 0; ni < 8; ++ni) o[ni][r] *= inv;
  }
  for (int ni = 0; ni < 8; ++ni) {
    int dd = ni * 16 + lr;
    for (int r = 0; r < 4; ++r) {
      int sg = q0 + w * 16 + lk * 4 + r;
      size_t tok = (size_t)sg * 8 + bb;
      if (dd < 64)
        aor[tok * 1024 + hh * 64 + dd] = f2bf(o[ni][r]);
      else
        aoi[tok * 1024 + hh * 64 + (dd - 64)] = f2bf(o[ni][r]);
    }
  }
}

// ---------------------------------------------------------------- out proj
// Combined [128][re32|im32] XOR-swizzled tiles; XCD swizzle (512 = 8 x 64).
__global__ __launch_bounds__(256, 2) void out_gemm(
    const unsigned short* __restrict__ ar, const unsigned short* __restrict__ ai,
    const unsigned short* __restrict__ wr, const unsigned short* __restrict__ wi,
    const float* __restrict__ br, const float* __restrict__ bi,
    float* __restrict__ out) {
  __shared__ __align__(16) unsigned short smem[16384];  // 32 KB
  unsigned short (*sA)[64] = (unsigned short (*)[64])(smem);
  unsigned short (*sW)[64] = (unsigned short (*)[64])(smem + 8192);

  const int tid = threadIdx.x;
  const int lane = tid & 63;
  const int w = tid >> 6;
  const int lr = lane & 15, lk = lane >> 4;
  const int wm = (w & 1) * 64, wn = (w >> 1) * 64;

  const int lin = blockIdx.x;
  const int wg = (lin & 7) * 64 + (lin >> 3);
  const int n0 = (wg & 7) * 128;
  const int m0 = (wg >> 3) * 128;

  int srow[4], sgsw[4];
  for (int c = 0; c < 4; ++c) {
    int gid = c * 256 + tid;
    srow[c] = gid >> 3;
    sgsw[c] = (gid & 7) ^ (srow[c] & 7);
  }

  f32x4 accre[4][4], accim[4][4];
  for (int i = 0; i < 4; ++i)
    for (int j = 0; j < 4; ++j) {
      accre[i][j] = {0.f, 0.f, 0.f, 0.f};
      accim[i][j] = {0.f, 0.f, 0.f, 0.f};
    }
  const u16x8 sign8 = {0x8000, 0x8000, 0x8000, 0x8000, 0x8000, 0x8000, 0x8000, 0x8000};

  for (int k0 = 0; k0 < 1024; k0 += 32) {
    for (int c = 0; c < 4; ++c) {
      int row = srow[c], gsw = sgsw[c];
      int kcol = k0 + (gsw & 3) * 8;
      size_t aoff = (size_t)(m0 + row) * 1024 + kcol;
      gload_lds16((gsw < 4 ? ar : ai) + aoff, smem + (c * 256 + w * 64) * 8);
      size_t woff = (size_t)(n0 + row) * 1024 + kcol;
      gload_lds16((gsw < 4 ? wr : wi) + woff, smem + 8192 + (c * 256 + w * 64) * 8);
    }
    __syncthreads();

    u16x8 fWr[4], fWi[4];
    for (int ni = 0; ni < 4; ++ni) {
      int R = wn + ni * 16 + lr, sw = R & 7;
      fWr[ni] = *(const u16x8*)&sW[R][(lk ^ sw) * 8];
      fWi[ni] = *(const u16x8*)&sW[R][((4 + lk) ^ sw) * 8];
    }
    for (int mi = 0; mi < 4; ++mi) {
      int R = wm + mi * 16 + lr, sw = R & 7;
      u16x8 a_r = *(const u16x8*)&sA[R][(lk ^ sw) * 8];
      u16x8 a_i = *(const u16x8*)&sA[R][((4 + lk) ^ sw) * 8];
      u16x8 na_i = a_i ^ sign8;
      for (int ni = 0; ni < 4; ++ni) {
        accre[mi][ni] = mfma_bf16(a_r, fWr[ni], accre[mi][ni]);
        accre[mi][ni] = mfma_bf16(na_i, fWi[ni], accre[mi][ni]);
        accim[mi][ni] = mfma_bf16(a_r, fWi[ni], accim[mi][ni]);
        accim[mi][ni] = mfma_bf16(a_i, fWr[ni], accim[mi][ni]);
      }
    }
    __syncthreads();
  }

  for (int ni = 0; ni < 4; ++ni) {
    int n = n0 + wn + ni * 16 + lr;
    float vbr = br[n], vbi = bi[n];
    for (int mi = 0; mi < 4; ++mi) {
      for (int r = 0; r < 4; ++r) {
        int m = m0 + wm + mi * 16 + lk * 4 + r;
        out[(size_t)m * 1024 + n] = accre[mi][ni][r] + vbr;
        out[8388608 + (size_t)m * 1024 + n] = accim[mi][ni][r] + vbi;
      }
    }
  }
}

// ---------------------------------------------------------------- launch
extern "C" void kernel_launch(void* const* d_in, const int* in_sizes, int n_in,
                              void* d_out, int out_size, void* d_ws, size_t ws_size,
                              hipStream_t stream) {
  const float* qre = (const float*)d_in[0];
  const float* qim = (const float*)d_in[1];
  const float* kre = (const float*)d_in[2];
  const float* kim = (const float*)d_in[3];
  const float* vre = (const float*)d_in[4];
  const float* vim = (const float*)d_in[5];
  const float* wqkv_re = (const float*)d_in[6];
  const float* wqkv_im = (const float*)d_in[7];
  const float* bqr = (const float*)d_in[8];
  const float* bqi = (const float*)d_in[9];
  const float* wo_re = (const float*)d_in[10];
  const float* wo_im = (const float*)d_in[11];
  const float* bor = (const float*)d_in[12];
  const float* boi = (const float*)d_in[13];

  char* ws = (char*)d_ws;
  unsigned short* wr_bf  = (unsigned short*)(ws + 0);          //  6.29 MB
  unsigned short* wi_bf  = (unsigned short*)(ws + 6291456);
  unsigned short* wor_bf = (unsigned short*)(ws + 12582912);
  unsigned short* woi_bf = (unsigned short*)(ws + 14680064);
  // activation bf16 (dead after proj_gemm)
  unsigned short* qreb   = (unsigned short*)(ws + 16777216);
  unsigned short* qimb   = (unsigned short*)(ws + 33554432);
  unsigned short* kreb   = (unsigned short*)(ws + 50331648);
  unsigned short* kimb   = (unsigned short*)(ws + 67108864);
  unsigned short* vreb   = (unsigned short*)(ws + 83886080);
  unsigned short* vimb   = (unsigned short*)(ws + 100663296);
  unsigned short* q2     = (unsigned short*)(ws + 117440512);  // 33.55 MB
  unsigned short* k2     = (unsigned short*)(ws + 150994944);
  unsigned short* vt     = (unsigned short*)(ws + 184549376);  // end 218.1 MB
  // attn outputs alias the dead activation region
  unsigned short* aor    = (unsigned short*)(ws + 16777216);
  unsigned short* aoi    = (unsigned short*)(ws + 33554432);

  cvt_kernel<<<3072, 256, 0, stream>>>(wqkv_re, wr_bf, 3145728);
  cvt_kernel<<<3072, 256, 0, stream>>>(wqkv_im, wi_bf, 3145728);
  cvt_kernel<<<1024, 256, 0, stream>>>(wo_re, wor_bf, 1048576);
  cvt_kernel<<<1024, 256, 0, stream>>>(wo_im, woi_bf, 1048576);
  cvt6_kernel<<<dim3(8192, 6), 256, 0, stream>>>(qre, qim, kre, kim, vre, vim,
                                                 qreb, qimb, kreb, kimb, vreb, vimb);

  proj_gemm<<<dim3(24, 64), 256, 0, stream>>>(qreb, qimb, kreb, kimb, vreb, vimb,
                                              wr_bf, wi_bf, bqr, bqi, q2, k2, vt);
  attn_kernel<<<dim3(128, 16), 256, 0, stream>>>(q2, k2, vt, aor, aoi);
  out_gemm<<<512, 256, 0, stream>>>(aor, aoi, wor_bf, woi_bf, bor, boi,
                                    (float*)d_out);
}